// Round 4
// baseline (158.744 us; speedup 1.0000x reference)
//
#include <hip/hip_runtime.h>
#include <hip/hip_bf16.h>
#include <stdint.h>

typedef __bf16 v8bf __attribute__((ext_vector_type(8)));
typedef float  v4f  __attribute__((ext_vector_type(4)));

#define LEAK 0.2f

static __device__ __forceinline__ unsigned short bf16rne(float f) {
    union { float f; uint32_t u; } v; v.f = f;
    return (unsigned short)((v.u + 0x7FFFu + ((v.u >> 16) & 1u)) >> 16);
}
static __device__ __forceinline__ float bf2f(unsigned short s) {
    union { uint32_t u; float f; } v; v.u = (uint32_t)s << 16; return v.f;
}
static __device__ __forceinline__ void gload16(const void* g, void* l) {
    __builtin_amdgcn_global_load_lds(
        (const __attribute__((address_space(1))) void*)g,
        (__attribute__((address_space(3))) void*)l, 16, 0, 0);
}

// ---------------------------------------------------------------------------
// K1 (LDS-free, absorbs old K0): Yt[j][n*60+lt] = bf16( sum_i x[n,i]*W[i,c] ),
// c = j*60+lt.  B-fragment read straight from W[i][c] row-major (B[k][col],
// k=i): per lane 8 scalars stride 3840, 4x64B segments/instr, L2-hot (16KB
// slab reused by 16 n-tile blocks).  A-fragment: contiguous float4 pairs of x.
// grid 960 = 16 nt * 60 ct, 256 threads.
// ---------------------------------------------------------------------------
__global__ __launch_bounds__(256) void k1_ygemm(const float* __restrict__ x,
                                                const float* __restrict__ W,
                                                unsigned short* __restrict__ Yt) {
    const int blk = blockIdx.x;
    const int nt = blk / 60, ct = blk % 60;
    const int n0 = nt * 64, c0 = ct * 64;
    const int t = threadIdx.x;
    const int w = t >> 6, l = t & 63;
    const int lr = l & 15, lg = l >> 4;

    v4f acc[4];
#pragma unroll
    for (int jt = 0; jt < 4; ++jt) acc[jt] = (v4f){0.f, 0.f, 0.f, 0.f};

    const float* xr = x + (n0 + 16 * w + lr) * 64;
#pragma unroll
    for (int s = 0; s < 2; ++s) {
        const float4 x0 = *reinterpret_cast<const float4*>(xr + s * 32 + lg * 8);
        const float4 x1 = *reinterpret_cast<const float4*>(xr + s * 32 + lg * 8 + 4);
        v8bf af;
        af[0] = (__bf16)x0.x; af[1] = (__bf16)x0.y;
        af[2] = (__bf16)x0.z; af[3] = (__bf16)x0.w;
        af[4] = (__bf16)x1.x; af[5] = (__bf16)x1.y;
        af[6] = (__bf16)x1.z; af[7] = (__bf16)x1.w;

        const float* wb = W + (size_t)(s * 32 + lg * 8) * 3840 + c0 + lr;
#pragma unroll
        for (int jt = 0; jt < 4; ++jt) {
            v8bf bf;
#pragma unroll
            for (int j = 0; j < 8; ++j) bf[j] = (__bf16)wb[(size_t)j * 3840 + jt * 16];
            acc[jt] = __builtin_amdgcn_mfma_f32_16x16x32_bf16(af, bf, acc[jt], 0, 0, 0);
        }
    }

#pragma unroll
    for (int jt = 0; jt < 4; ++jt) {
#pragma unroll
        for (int r = 0; r < 4; ++r) {
            const int n = n0 + 16 * w + lg * 4 + r;
            const int c = c0 + jt * 16 + lr;
            const int j = c / 60, lt = c % 60;
            Yt[j * 61440 + n * 60 + lt] = bf16rne(acc[jt][r]);
        }
    }
}

// ---------------------------------------------------------------------------
// K2: split-K GEMM (3-buffer 2-deep counted-vmcnt DMA pipeline, unchanged
// core) + bf16 partials + last-block-reduces epilogue (absorbs old K3).
// partial[ks][m][j] = sum_{k in 1920-chunk} adj[m][k]*Yt[j][k]  (bf16)
// grid 512 = 16 m-tiles * 32 k-splits, 256 threads, 30 BK=64 steps.
// Epilogue: 32nd finisher of each m-tile sums partials in FIXED sp order
// (bitwise deterministic), adds x@W2 skip, lrelu, writes out.
// ---------------------------------------------------------------------------
__global__ __launch_bounds__(256) void k2_main(const float* __restrict__ adj,
                                               const unsigned short* __restrict__ Yt,
                                               const float* __restrict__ x,
                                               const float* __restrict__ W2,
                                               unsigned short* __restrict__ partial,
                                               int* __restrict__ cnt,
                                               float* __restrict__ out) {
    __shared__ __align__(16) char lds[73728];
    __shared__ int is_last;
    const int blk = blockIdx.x;
    const int mt = blk >> 5, ks = blk & 31;      // blk%8 == ks%8 -> Yt XCD locality
    const int m0 = mt * 64;
    const long kc0 = (long)ks * 1920;
    const int t = threadIdx.x;
    const int w = t >> 6, l = t & 63;
    const int lr = l & 15, lg = l >> 4;

    const char* srcA[4];
    const char* srcB[2];
#pragma unroll
    for (int k = 0; k < 4; ++k) {
        const int row = k * 16 + w * 4 + lg;
        srcA[k] = (const char*)(adj + (size_t)(m0 + row) * 61440 + kc0)
                  + ((lr * 16) ^ ((row & 7) << 4));
    }
#pragma unroll
    for (int k = 0; k < 2; ++k) {
        const int row = k * 32 + w * 8 + (l >> 3);
        srcB[k] = (const char*)(Yt + (size_t)row * 61440 + kc0)
                  + (((l & 7) * 16) ^ ((row & 7) << 4));
    }

#define STAGE(bs, s) do {                                                      \
        char* ab_ = lds + (bs) * 16384;                                        \
        char* bb_ = lds + 49152 + (bs) * 8192;                                 \
        _Pragma("unroll")                                                      \
        for (int k_ = 0; k_ < 4; ++k_)                                         \
            gload16(srcA[k_] + (size_t)(s) * 256, ab_ + k_ * 4096 + w * 1024); \
        _Pragma("unroll")                                                      \
        for (int k_ = 0; k_ < 2; ++k_)                                         \
            gload16(srcB[k_] + (size_t)(s) * 128, bb_ + k_ * 4096 + w * 1024); \
    } while (0)

    v4f acc[4];
#pragma unroll
    for (int jt = 0; jt < 4; ++jt) acc[jt] = (v4f){0.f, 0.f, 0.f, 0.f};

    const int ar = 16 * w + lr;
    const int sa = (ar & 7) << 4;

    STAGE(0, 0);
    STAGE(1, 1);
    int bs = 2, bc = 0;

#pragma unroll 1
    for (int i = 0; i < 30; ++i) {
        if (i < 29) { asm volatile("s_waitcnt vmcnt(6)" ::: "memory"); }
        else        { asm volatile("s_waitcnt vmcnt(0)" ::: "memory"); }
        __builtin_amdgcn_s_barrier();
        asm volatile("" ::: "memory");
        if (i < 28) STAGE(bs, i + 2);

        const char* ab = lds + bc * 16384;
        const char* bb = lds + 49152 + bc * 8192;
        v8bf af[2];
#pragma unroll
        for (int ss = 0; ss < 2; ++ss) {
            const int Xf = ss * 128 + lg * 32;
            const float4 x0 = *reinterpret_cast<const float4*>(ab + ar * 256 + (Xf ^ sa));
            const float4 x1 = *reinterpret_cast<const float4*>(ab + ar * 256 + ((Xf + 16) ^ sa));
            v8bf f;
            f[0] = (__bf16)x0.x; f[1] = (__bf16)x0.y;
            f[2] = (__bf16)x0.z; f[3] = (__bf16)x0.w;
            f[4] = (__bf16)x1.x; f[5] = (__bf16)x1.y;
            f[6] = (__bf16)x1.z; f[7] = (__bf16)x1.w;
            af[ss] = f;
        }
#pragma unroll
        for (int jt = 0; jt < 4; ++jt) {
            const int br = 16 * jt + lr;
            const int sb = (br & 7) << 4;
            const v8bf b0 = *reinterpret_cast<const v8bf*>(bb + br * 128 + ((lg * 16) ^ sb));
            const v8bf b1 = *reinterpret_cast<const v8bf*>(bb + br * 128 + ((64 + lg * 16) ^ sb));
            acc[jt] = __builtin_amdgcn_mfma_f32_16x16x32_bf16(af[0], b0, acc[jt], 0, 0, 0);
            acc[jt] = __builtin_amdgcn_mfma_f32_16x16x32_bf16(af[1], b1, acc[jt], 0, 0, 0);
        }

        bs = (bs == 2) ? 0 : bs + 1;
        bc = (bc == 2) ? 0 : bc + 1;
    }
#undef STAGE

    // bf16 partial store
    unsigned short* const p = partial + (size_t)ks * 65536;
#pragma unroll
    for (int jt = 0; jt < 4; ++jt) {
#pragma unroll
        for (int r = 0; r < 4; ++r) {
            const int m = m0 + 16 * w + lg * 4 + r;
            const int j = jt * 16 + lr;
            p[m * 64 + j] = bf16rne(acc[jt][r]);
        }
    }

    // last-block-reduces epilogue (deterministic: fixed sp sum order)
    __threadfence();
    __syncthreads();
    if (t == 0) {
        const int old = __hip_atomic_fetch_add(cnt + mt, 1, __ATOMIC_ACQ_REL,
                                               __HIP_MEMORY_SCOPE_AGENT);
        is_last = (old == 31);
    }
    __syncthreads();
    if (!is_last) return;
    __threadfence();

    const int ml = t >> 2;                 // 0..63
    const int j0 = (t & 3) * 16;           // 0,16,32,48
    const int m = m0 + ml;

    float accf[16];
#pragma unroll
    for (int e = 0; e < 16; ++e) accf[e] = 0.f;

#pragma unroll 4
    for (int sp = 0; sp < 32; ++sp) {
        const unsigned short* pp = partial + (size_t)sp * 65536 + m * 64 + j0;
        const uint4 a = *reinterpret_cast<const uint4*>(pp);
        const uint4 b = *reinterpret_cast<const uint4*>(pp + 8);
        accf[0]  += bf2f((unsigned short)(a.x & 0xffff));
        accf[1]  += bf2f((unsigned short)(a.x >> 16));
        accf[2]  += bf2f((unsigned short)(a.y & 0xffff));
        accf[3]  += bf2f((unsigned short)(a.y >> 16));
        accf[4]  += bf2f((unsigned short)(a.z & 0xffff));
        accf[5]  += bf2f((unsigned short)(a.z >> 16));
        accf[6]  += bf2f((unsigned short)(a.w & 0xffff));
        accf[7]  += bf2f((unsigned short)(a.w >> 16));
        accf[8]  += bf2f((unsigned short)(b.x & 0xffff));
        accf[9]  += bf2f((unsigned short)(b.x >> 16));
        accf[10] += bf2f((unsigned short)(b.y & 0xffff));
        accf[11] += bf2f((unsigned short)(b.y >> 16));
        accf[12] += bf2f((unsigned short)(b.z & 0xffff));
        accf[13] += bf2f((unsigned short)(b.z >> 16));
        accf[14] += bf2f((unsigned short)(b.w & 0xffff));
        accf[15] += bf2f((unsigned short)(b.w >> 16));
    }

    const float* xrow = x + m * 64;
#pragma unroll 4
    for (int i = 0; i < 64; ++i) {
        const float xv = xrow[i];
        const float4 w0 = *reinterpret_cast<const float4*>(W2 + i * 64 + j0);
        const float4 w1 = *reinterpret_cast<const float4*>(W2 + i * 64 + j0 + 4);
        const float4 w2 = *reinterpret_cast<const float4*>(W2 + i * 64 + j0 + 8);
        const float4 w3 = *reinterpret_cast<const float4*>(W2 + i * 64 + j0 + 12);
        accf[0]  += xv * w0.x; accf[1]  += xv * w0.y;
        accf[2]  += xv * w0.z; accf[3]  += xv * w0.w;
        accf[4]  += xv * w1.x; accf[5]  += xv * w1.y;
        accf[6]  += xv * w1.z; accf[7]  += xv * w1.w;
        accf[8]  += xv * w2.x; accf[9]  += xv * w2.y;
        accf[10] += xv * w2.z; accf[11] += xv * w2.w;
        accf[12] += xv * w3.x; accf[13] += xv * w3.y;
        accf[14] += xv * w3.z; accf[15] += xv * w3.w;
    }

#pragma unroll
    for (int q = 0; q < 4; ++q) {
        float4 o;
        o.x = fmaxf(accf[q * 4 + 0], LEAK * accf[q * 4 + 0]);
        o.y = fmaxf(accf[q * 4 + 1], LEAK * accf[q * 4 + 1]);
        o.z = fmaxf(accf[q * 4 + 2], LEAK * accf[q * 4 + 2]);
        o.w = fmaxf(accf[q * 4 + 3], LEAK * accf[q * 4 + 3]);
        *reinterpret_cast<float4*>(out + m * 64 + j0 + q * 4) = o;
    }
}

// ---------------------------------------------------------------------------
extern "C" void kernel_launch(void* const* d_in, const int* in_sizes, int n_in,
                              void* d_out, int out_size, void* d_ws, size_t ws_size,
                              hipStream_t stream) {
    const float* x   = (const float*)d_in[0];
    const float* adj = (const float*)d_in[1];
    const float* W   = (const float*)d_in[2];
    const float* W2  = (const float*)d_in[3];
    float* out = (float*)d_out;

    char* ws = (char*)d_ws;
    unsigned short* Yt      = (unsigned short*)ws;               // 7,864,320 B
    unsigned short* partial = (unsigned short*)(ws + 7864320);   // 4,194,304 B
    int* cnt                = (int*)(ws + 12058624);             // 64 B

    hipMemsetAsync(cnt, 0, 16 * sizeof(int), stream);
    k1_ygemm<<<960, 256, 0, stream>>>(x, W, Yt);
    k2_main <<<512, 256, 0, stream>>>(adj, Yt, x, W2, partial, cnt, out);
}

// Round 5
// 58.780 us; speedup vs baseline: 2.7006x; 2.7006x over previous
//
#include <hip/hip_runtime.h>
#include <hip/hip_bf16.h>
#include <stdint.h>

typedef __bf16 v8bf __attribute__((ext_vector_type(8)));
typedef float  v4f  __attribute__((ext_vector_type(4)));

#define LEAK 0.2f

static __device__ __forceinline__ unsigned short bf16rne(float f) {
    union { float f; uint32_t u; } v; v.f = f;
    return (unsigned short)((v.u + 0x7FFFu + ((v.u >> 16) & 1u)) >> 16);
}
static __device__ __forceinline__ float bf2f(unsigned short s) {
    union { uint32_t u; float f; } v; v.u = (uint32_t)s << 16; return v.f;
}
static __device__ __forceinline__ void gload16(const void* g, void* l) {
    __builtin_amdgcn_global_load_lds(
        (const __attribute__((address_space(1))) void*)g,
        (__attribute__((address_space(3))) void*)l, 16, 0, 0);
}

// ---------------------------------------------------------------------------
// K1 (LDS-free): Yt[j][n*60+lt] = bf16( sum_i x[n,i]*W[i,c] ), c = j*60+lt.
// B-fragment straight from W[i][c] row-major; A-fragment from x float4 pairs.
// grid 960 = 16 nt * 60 ct, 256 threads.  (proven in R4)
// ---------------------------------------------------------------------------
__global__ __launch_bounds__(256) void k1_ygemm(const float* __restrict__ x,
                                                const float* __restrict__ W,
                                                unsigned short* __restrict__ Yt) {
    const int blk = blockIdx.x;
    const int nt = blk / 60, ct = blk % 60;
    const int n0 = nt * 64, c0 = ct * 64;
    const int t = threadIdx.x;
    const int w = t >> 6, l = t & 63;
    const int lr = l & 15, lg = l >> 4;

    v4f acc[4];
#pragma unroll
    for (int jt = 0; jt < 4; ++jt) acc[jt] = (v4f){0.f, 0.f, 0.f, 0.f};

    const float* xr = x + (n0 + 16 * w + lr) * 64;
#pragma unroll
    for (int s = 0; s < 2; ++s) {
        const float4 x0 = *reinterpret_cast<const float4*>(xr + s * 32 + lg * 8);
        const float4 x1 = *reinterpret_cast<const float4*>(xr + s * 32 + lg * 8 + 4);
        v8bf af;
        af[0] = (__bf16)x0.x; af[1] = (__bf16)x0.y;
        af[2] = (__bf16)x0.z; af[3] = (__bf16)x0.w;
        af[4] = (__bf16)x1.x; af[5] = (__bf16)x1.y;
        af[6] = (__bf16)x1.z; af[7] = (__bf16)x1.w;

        const float* wb = W + (size_t)(s * 32 + lg * 8) * 3840 + c0 + lr;
#pragma unroll
        for (int jt = 0; jt < 4; ++jt) {
            v8bf bf;
#pragma unroll
            for (int j = 0; j < 8; ++j) bf[j] = (__bf16)wb[(size_t)j * 3840 + jt * 16];
            acc[jt] = __builtin_amdgcn_mfma_f32_16x16x32_bf16(af, bf, acc[jt], 0, 0, 0);
        }
    }

#pragma unroll
    for (int jt = 0; jt < 4; ++jt) {
#pragma unroll
        for (int r = 0; r < 4; ++r) {
            const int n = n0 + 16 * w + lg * 4 + r;
            const int c = c0 + jt * 16 + lr;
            const int j = c / 60, lt = c % 60;
            Yt[j * 61440 + n * 60 + lt] = bf16rne(acc[jt][r]);
        }
    }
}

// ---------------------------------------------------------------------------
// K2: split-K GEMM, 3-buffer 2-deep counted-vmcnt DMA pipeline (R3-proven
// core, NO fences, NO epilogue).  bf16 partial stores.
// partial[ks][m][j] = bf16( sum_{k in 1920-chunk} adj[m][k]*Yt[j][k] )
// grid 512 = 16 m-tiles * 32 k-splits, 256 threads, 30 BK=64 steps.
// ---------------------------------------------------------------------------
__global__ __launch_bounds__(256) void k2_main(const float* __restrict__ adj,
                                               const unsigned short* __restrict__ Yt,
                                               unsigned short* __restrict__ partial) {
    __shared__ __align__(16) char lds[73728];
    const int blk = blockIdx.x;
    const int mt = blk >> 5, ks = blk & 31;      // blk%8 == ks%8 -> Yt XCD locality
    const int m0 = mt * 64;
    const long kc0 = (long)ks * 1920;
    const int t = threadIdx.x;
    const int w = t >> 6, l = t & 63;
    const int lr = l & 15, lg = l >> 4;

    const char* srcA[4];
    const char* srcB[2];
#pragma unroll
    for (int k = 0; k < 4; ++k) {
        const int row = k * 16 + w * 4 + lg;
        srcA[k] = (const char*)(adj + (size_t)(m0 + row) * 61440 + kc0)
                  + ((lr * 16) ^ ((row & 7) << 4));
    }
#pragma unroll
    for (int k = 0; k < 2; ++k) {
        const int row = k * 32 + w * 8 + (l >> 3);
        srcB[k] = (const char*)(Yt + (size_t)row * 61440 + kc0)
                  + (((l & 7) * 16) ^ ((row & 7) << 4));
    }

#define STAGE(bs, s) do {                                                      \
        char* ab_ = lds + (bs) * 16384;                                        \
        char* bb_ = lds + 49152 + (bs) * 8192;                                 \
        _Pragma("unroll")                                                      \
        for (int k_ = 0; k_ < 4; ++k_)                                         \
            gload16(srcA[k_] + (size_t)(s) * 256, ab_ + k_ * 4096 + w * 1024); \
        _Pragma("unroll")                                                      \
        for (int k_ = 0; k_ < 2; ++k_)                                         \
            gload16(srcB[k_] + (size_t)(s) * 128, bb_ + k_ * 4096 + w * 1024); \
    } while (0)

    v4f acc[4];
#pragma unroll
    for (int jt = 0; jt < 4; ++jt) acc[jt] = (v4f){0.f, 0.f, 0.f, 0.f};

    const int ar = 16 * w + lr;
    const int sa = (ar & 7) << 4;

    STAGE(0, 0);
    STAGE(1, 1);
    int bs = 2, bc = 0;

#pragma unroll 1
    for (int i = 0; i < 30; ++i) {
        if (i < 29) { asm volatile("s_waitcnt vmcnt(6)" ::: "memory"); }
        else        { asm volatile("s_waitcnt vmcnt(0)" ::: "memory"); }
        __builtin_amdgcn_s_barrier();
        asm volatile("" ::: "memory");
        if (i < 28) STAGE(bs, i + 2);

        const char* ab = lds + bc * 16384;
        const char* bb = lds + 49152 + bc * 8192;
        v8bf af[2];
#pragma unroll
        for (int ss = 0; ss < 2; ++ss) {
            const int Xf = ss * 128 + lg * 32;
            const float4 x0 = *reinterpret_cast<const float4*>(ab + ar * 256 + (Xf ^ sa));
            const float4 x1 = *reinterpret_cast<const float4*>(ab + ar * 256 + ((Xf + 16) ^ sa));
            v8bf f;
            f[0] = (__bf16)x0.x; f[1] = (__bf16)x0.y;
            f[2] = (__bf16)x0.z; f[3] = (__bf16)x0.w;
            f[4] = (__bf16)x1.x; f[5] = (__bf16)x1.y;
            f[6] = (__bf16)x1.z; f[7] = (__bf16)x1.w;
            af[ss] = f;
        }
#pragma unroll
        for (int jt = 0; jt < 4; ++jt) {
            const int br = 16 * jt + lr;
            const int sb = (br & 7) << 4;
            const v8bf b0 = *reinterpret_cast<const v8bf*>(bb + br * 128 + ((lg * 16) ^ sb));
            const v8bf b1 = *reinterpret_cast<const v8bf*>(bb + br * 128 + ((64 + lg * 16) ^ sb));
            acc[jt] = __builtin_amdgcn_mfma_f32_16x16x32_bf16(af[0], b0, acc[jt], 0, 0, 0);
            acc[jt] = __builtin_amdgcn_mfma_f32_16x16x32_bf16(af[1], b1, acc[jt], 0, 0, 0);
        }

        bs = (bs == 2) ? 0 : bs + 1;
        bc = (bc == 2) ? 0 : bc + 1;
    }
#undef STAGE

    unsigned short* const p = partial + (size_t)ks * 65536;
#pragma unroll
    for (int jt = 0; jt < 4; ++jt) {
#pragma unroll
        for (int r = 0; r < 4; ++r) {
            const int m = m0 + 16 * w + lg * 4 + r;
            const int j = jt * 16 + lr;
            p[m * 64 + j] = bf16rne(acc[jt][r]);
        }
    }
}

// ---------------------------------------------------------------------------
// K3: out = lrelu( sum_splits partial(bf16) + x @ W2 )
// 8192 threads; each handles one m and 8 j's (uint4 partial loads).
// ---------------------------------------------------------------------------
__global__ __launch_bounds__(256) void k3_epi(const unsigned short* __restrict__ partial,
                                              const float* __restrict__ x,
                                              const float* __restrict__ W2,
                                              float* __restrict__ out) {
    const int idx8 = blockIdx.x * 256 + threadIdx.x;   // 0..8191
    const int m = idx8 >> 3;
    const int j0 = (idx8 & 7) * 8;

    float accf[8];
#pragma unroll
    for (int e = 0; e < 8; ++e) accf[e] = 0.f;

#pragma unroll 8
    for (int sp = 0; sp < 32; ++sp) {
        const uint4 a = *reinterpret_cast<const uint4*>(
            partial + (size_t)sp * 65536 + m * 64 + j0);
        accf[0] += bf2f((unsigned short)(a.x & 0xffff));
        accf[1] += bf2f((unsigned short)(a.x >> 16));
        accf[2] += bf2f((unsigned short)(a.y & 0xffff));
        accf[3] += bf2f((unsigned short)(a.y >> 16));
        accf[4] += bf2f((unsigned short)(a.z & 0xffff));
        accf[5] += bf2f((unsigned short)(a.z >> 16));
        accf[6] += bf2f((unsigned short)(a.w & 0xffff));
        accf[7] += bf2f((unsigned short)(a.w >> 16));
    }

    const float* xrow = x + m * 64;
#pragma unroll 4
    for (int i = 0; i < 64; ++i) {
        const float xv = xrow[i];
        const float4 w0 = *reinterpret_cast<const float4*>(W2 + i * 64 + j0);
        const float4 w1 = *reinterpret_cast<const float4*>(W2 + i * 64 + j0 + 4);
        accf[0] += xv * w0.x; accf[1] += xv * w0.y;
        accf[2] += xv * w0.z; accf[3] += xv * w0.w;
        accf[4] += xv * w1.x; accf[5] += xv * w1.y;
        accf[6] += xv * w1.z; accf[7] += xv * w1.w;
    }

#pragma unroll
    for (int q = 0; q < 2; ++q) {
        float4 o;
        o.x = fmaxf(accf[q * 4 + 0], LEAK * accf[q * 4 + 0]);
        o.y = fmaxf(accf[q * 4 + 1], LEAK * accf[q * 4 + 1]);
        o.z = fmaxf(accf[q * 4 + 2], LEAK * accf[q * 4 + 2]);
        o.w = fmaxf(accf[q * 4 + 3], LEAK * accf[q * 4 + 3]);
        *reinterpret_cast<float4*>(out + m * 64 + j0 + q * 4) = o;
    }
}

// ---------------------------------------------------------------------------
extern "C" void kernel_launch(void* const* d_in, const int* in_sizes, int n_in,
                              void* d_out, int out_size, void* d_ws, size_t ws_size,
                              hipStream_t stream) {
    const float* x   = (const float*)d_in[0];
    const float* adj = (const float*)d_in[1];
    const float* W   = (const float*)d_in[2];
    const float* W2  = (const float*)d_in[3];
    float* out = (float*)d_out;

    char* ws = (char*)d_ws;
    unsigned short* Yt      = (unsigned short*)ws;               // 7,864,320 B
    unsigned short* partial = (unsigned short*)(ws + 7864320);   // 4,194,304 B

    k1_ygemm<<<960, 256, 0, stream>>>(x, W, Yt);
    k2_main <<<512, 256, 0, stream>>>(adj, Yt, partial);
    k3_epi  <<<32,  256, 0, stream>>>(partial, x, W2, out);
}

// Round 6
// 54.365 us; speedup vs baseline: 2.9200x; 1.0812x over previous
//
#include <hip/hip_runtime.h>
#include <hip/hip_bf16.h>
#include <stdint.h>

typedef __bf16 v8bf __attribute__((ext_vector_type(8)));
typedef float  v4f  __attribute__((ext_vector_type(4)));

#define LEAK 0.2f

static __device__ __forceinline__ unsigned short bf16rne(float f) {
    union { float f; uint32_t u; } v; v.f = f;
    return (unsigned short)((v.u + 0x7FFFu + ((v.u >> 16) & 1u)) >> 16);
}
static __device__ __forceinline__ float bf2f(unsigned short s) {
    union { uint32_t u; float f; } v; v.u = (uint32_t)s << 16; return v.f;
}
static __device__ __forceinline__ void gload16(const void* g, void* l) {
    __builtin_amdgcn_global_load_lds(
        (const __attribute__((address_space(1))) void*)g,
        (__attribute__((address_space(3))) void*)l, 16, 0, 0);
}

// ---------------------------------------------------------------------------
// K1: Yt[j][n*60+lt] = bf16( sum_i x[n,i]*W[i,c] ), c = j*60+lt.
// x-slab (16KB f32) staged via DMA (pre-swizzled source, K2's proven pattern).
// W-slab transposed to bf16 Wt[c][i] in LDS via reg-staging (coalesced float4
// reads, one-time b16 scatter writes).  B-fragment = single ds_read_b128.
// grid 960 = 16 nt * 60 ct, 256 threads.
// ---------------------------------------------------------------------------
__global__ __launch_bounds__(256) void k1_ygemm(const float* __restrict__ x,
                                                const float* __restrict__ W,
                                                unsigned short* __restrict__ Yt) {
    __shared__ __align__(16) char lds[24576];   // xs f32 16KB | wt bf16 8KB
    const int blk = blockIdx.x;
    const int nt = blk / 60, ct = blk % 60;
    const int n0 = nt * 64, c0 = ct * 64;
    const int t = threadIdx.x;
    const int w = t >> 6, l = t & 63;
    const int lr = l & 15, lg = l >> 4;

    // stage x rows (f32, 256B rows, swizzled source + linear LDS dest)
#pragma unroll
    for (int k = 0; k < 4; ++k) {
        const int row = k * 16 + w * 4 + lg;
        const char* src = (const char*)(x + (size_t)(n0 + row) * 64)
                          + ((lr * 16) ^ ((row & 7) << 4));
        gload16(src, lds + k * 4096 + w * 1024);
    }
    // stage Wt[c][i] bf16 (reg transpose; swizzle ((c&7)<<4))
#pragma unroll
    for (int r = 0; r < 4; ++r) {
        const int q = t + (r << 8);          // 0..1023
        const int i = q >> 4;                // 0..63
        const int c4 = (q & 15) << 2;        // 0..60
        const float4 v = *reinterpret_cast<const float4*>(W + (size_t)i * 3840 + c0 + c4);
        const unsigned short b0 = bf16rne(v.x), b1 = bf16rne(v.y);
        const unsigned short b2 = bf16rne(v.z), b3 = bf16rne(v.w);
#pragma unroll
        for (int e = 0; e < 4; ++e) {
            const int c = c4 + e;
            const unsigned short bv = (e == 0) ? b0 : (e == 1) ? b1 : (e == 2) ? b2 : b3;
            *(unsigned short*)(lds + 16384 + c * 128 + ((i * 2) ^ ((c & 7) << 4))) = bv;
        }
    }
    __syncthreads();

    v4f acc[4];
#pragma unroll
    for (int jt = 0; jt < 4; ++jt) acc[jt] = (v4f){0.f, 0.f, 0.f, 0.f};

    const int ar = 16 * w + lr;
    const int sa = (ar & 7) << 4;

#pragma unroll
    for (int s = 0; s < 2; ++s) {
        const int Xf = s * 128 + lg * 32;
        const float4 x0 = *reinterpret_cast<const float4*>(lds + ar * 256 + (Xf ^ sa));
        const float4 x1 = *reinterpret_cast<const float4*>(lds + ar * 256 + ((Xf + 16) ^ sa));
        v8bf af;
        af[0] = (__bf16)x0.x; af[1] = (__bf16)x0.y;
        af[2] = (__bf16)x0.z; af[3] = (__bf16)x0.w;
        af[4] = (__bf16)x1.x; af[5] = (__bf16)x1.y;
        af[6] = (__bf16)x1.z; af[7] = (__bf16)x1.w;

#pragma unroll
        for (int jt = 0; jt < 4; ++jt) {
            const int c = jt * 16 + lr;
            const v8bf bf = *reinterpret_cast<const v8bf*>(
                lds + 16384 + c * 128 + ((s * 64 + lg * 16) ^ ((c & 7) << 4)));
            acc[jt] = __builtin_amdgcn_mfma_f32_16x16x32_bf16(af, bf, acc[jt], 0, 0, 0);
        }
    }

#pragma unroll
    for (int jt = 0; jt < 4; ++jt) {
#pragma unroll
        for (int r = 0; r < 4; ++r) {
            const int n = n0 + 16 * w + lg * 4 + r;
            const int c = c0 + jt * 16 + lr;
            const int j = c / 60, lt = c % 60;
            Yt[j * 61440 + n * 60 + lt] = bf16rne(acc[jt][r]);
        }
    }
}

// ---------------------------------------------------------------------------
// K2: split-K GEMM, 3-buffer 2-deep counted-vmcnt DMA pipeline (R3/R5-proven
// core, unchanged).  bf16 partial stores.
// partial[ks][m][j] = bf16( sum_{k in 1920-chunk} adj[m][k]*Yt[j][k] )
// grid 512 = 16 m-tiles * 32 k-splits, 256 threads, 30 BK=64 steps.
// ---------------------------------------------------------------------------
__global__ __launch_bounds__(256) void k2_main(const float* __restrict__ adj,
                                               const unsigned short* __restrict__ Yt,
                                               unsigned short* __restrict__ partial) {
    __shared__ __align__(16) char lds[73728];
    const int blk = blockIdx.x;
    const int mt = blk >> 5, ks = blk & 31;      // blk%8 == ks%8 -> Yt XCD locality
    const int m0 = mt * 64;
    const long kc0 = (long)ks * 1920;
    const int t = threadIdx.x;
    const int w = t >> 6, l = t & 63;
    const int lr = l & 15, lg = l >> 4;

    const char* srcA[4];
    const char* srcB[2];
#pragma unroll
    for (int k = 0; k < 4; ++k) {
        const int row = k * 16 + w * 4 + lg;
        srcA[k] = (const char*)(adj + (size_t)(m0 + row) * 61440 + kc0)
                  + ((lr * 16) ^ ((row & 7) << 4));
    }
#pragma unroll
    for (int k = 0; k < 2; ++k) {
        const int row = k * 32 + w * 8 + (l >> 3);
        srcB[k] = (const char*)(Yt + (size_t)row * 61440 + kc0)
                  + (((l & 7) * 16) ^ ((row & 7) << 4));
    }

#define STAGE(bs, s) do {                                                      \
        char* ab_ = lds + (bs) * 16384;                                        \
        char* bb_ = lds + 49152 + (bs) * 8192;                                 \
        _Pragma("unroll")                                                      \
        for (int k_ = 0; k_ < 4; ++k_)                                         \
            gload16(srcA[k_] + (size_t)(s) * 256, ab_ + k_ * 4096 + w * 1024); \
        _Pragma("unroll")                                                      \
        for (int k_ = 0; k_ < 2; ++k_)                                         \
            gload16(srcB[k_] + (size_t)(s) * 128, bb_ + k_ * 4096 + w * 1024); \
    } while (0)

    v4f acc[4];
#pragma unroll
    for (int jt = 0; jt < 4; ++jt) acc[jt] = (v4f){0.f, 0.f, 0.f, 0.f};

    const int ar = 16 * w + lr;
    const int sa = (ar & 7) << 4;

    STAGE(0, 0);
    STAGE(1, 1);
    int bs = 2, bc = 0;

#pragma unroll 1
    for (int i = 0; i < 30; ++i) {
        if (i < 29) { asm volatile("s_waitcnt vmcnt(6)" ::: "memory"); }
        else        { asm volatile("s_waitcnt vmcnt(0)" ::: "memory"); }
        __builtin_amdgcn_s_barrier();
        asm volatile("" ::: "memory");
        if (i < 28) STAGE(bs, i + 2);

        const char* ab = lds + bc * 16384;
        const char* bb = lds + 49152 + bc * 8192;
        v8bf af[2];
#pragma unroll
        for (int ss = 0; ss < 2; ++ss) {
            const int Xf = ss * 128 + lg * 32;
            const float4 x0 = *reinterpret_cast<const float4*>(ab + ar * 256 + (Xf ^ sa));
            const float4 x1 = *reinterpret_cast<const float4*>(ab + ar * 256 + ((Xf + 16) ^ sa));
            v8bf f;
            f[0] = (__bf16)x0.x; f[1] = (__bf16)x0.y;
            f[2] = (__bf16)x0.z; f[3] = (__bf16)x0.w;
            f[4] = (__bf16)x1.x; f[5] = (__bf16)x1.y;
            f[6] = (__bf16)x1.z; f[7] = (__bf16)x1.w;
            af[ss] = f;
        }
#pragma unroll
        for (int jt = 0; jt < 4; ++jt) {
            const int br = 16 * jt + lr;
            const int sb = (br & 7) << 4;
            const v8bf b0 = *reinterpret_cast<const v8bf*>(bb + br * 128 + ((lg * 16) ^ sb));
            const v8bf b1 = *reinterpret_cast<const v8bf*>(bb + br * 128 + ((64 + lg * 16) ^ sb));
            acc[jt] = __builtin_amdgcn_mfma_f32_16x16x32_bf16(af[0], b0, acc[jt], 0, 0, 0);
            acc[jt] = __builtin_amdgcn_mfma_f32_16x16x32_bf16(af[1], b1, acc[jt], 0, 0, 0);
        }

        bs = (bs == 2) ? 0 : bs + 1;
        bc = (bc == 2) ? 0 : bc + 1;
    }
#undef STAGE

    unsigned short* const p = partial + (size_t)ks * 65536;
#pragma unroll
    for (int jt = 0; jt < 4; ++jt) {
#pragma unroll
        for (int r = 0; r < 4; ++r) {
            const int m = m0 + 16 * w + lg * 4 + r;
            const int j = jt * 16 + lr;
            p[m * 64 + j] = bf16rne(acc[jt][r]);
        }
    }
}

// ---------------------------------------------------------------------------
// K3: out = lrelu( sum_splits partial(bf16) + x @ W2 )
// 16384 threads (64 blocks); each handles one m and 4 j's; fully coalesced.
// ---------------------------------------------------------------------------
__global__ __launch_bounds__(256) void k3_epi(const unsigned short* __restrict__ partial,
                                              const float* __restrict__ x,
                                              const float* __restrict__ W2,
                                              float* __restrict__ out) {
    const int idx = blockIdx.x * 256 + threadIdx.x;   // 0..16383
    const int m = idx >> 4;
    const int j0 = (idx & 15) * 4;

    float a0 = 0.f, a1 = 0.f, a2 = 0.f, a3 = 0.f;
#pragma unroll 8
    for (int sp = 0; sp < 32; ++sp) {
        const uint2 a = *reinterpret_cast<const uint2*>(
            partial + (size_t)sp * 65536 + m * 64 + j0);
        a0 += bf2f((unsigned short)(a.x & 0xffff));
        a1 += bf2f((unsigned short)(a.x >> 16));
        a2 += bf2f((unsigned short)(a.y & 0xffff));
        a3 += bf2f((unsigned short)(a.y >> 16));
    }

    const float* xrow = x + m * 64;
#pragma unroll 8
    for (int i = 0; i < 64; ++i) {
        const float xv = xrow[i];
        const float4 wv = *reinterpret_cast<const float4*>(W2 + i * 64 + j0);
        a0 += xv * wv.x; a1 += xv * wv.y;
        a2 += xv * wv.z; a3 += xv * wv.w;
    }

    float4 o;
    o.x = fmaxf(a0, LEAK * a0);
    o.y = fmaxf(a1, LEAK * a1);
    o.z = fmaxf(a2, LEAK * a2);
    o.w = fmaxf(a3, LEAK * a3);
    *reinterpret_cast<float4*>(out + m * 64 + j0) = o;
}

// ---------------------------------------------------------------------------
extern "C" void kernel_launch(void* const* d_in, const int* in_sizes, int n_in,
                              void* d_out, int out_size, void* d_ws, size_t ws_size,
                              hipStream_t stream) {
    const float* x   = (const float*)d_in[0];
    const float* adj = (const float*)d_in[1];
    const float* W   = (const float*)d_in[2];
    const float* W2  = (const float*)d_in[3];
    float* out = (float*)d_out;

    char* ws = (char*)d_ws;
    unsigned short* Yt      = (unsigned short*)ws;               // 7,864,320 B
    unsigned short* partial = (unsigned short*)(ws + 7864320);   // 4,194,304 B

    k1_ygemm<<<960, 256, 0, stream>>>(x, W, Yt);
    k2_main <<<512, 256, 0, stream>>>(adj, Yt, partial);
    k3_epi  <<<64,  256, 0, stream>>>(partial, x, W2, out);
}